// Round 2
// baseline (236.807 us; speedup 1.0000x reference)
//
#include <hip/hip_runtime.h>

#define MM 576      // H*W
#define NBLK 64     // grid size; must be <= 256 for guaranteed co-residency

__device__ __forceinline__ float lrelu(float x) { return x > 0.f ? x : 0.2f * x; }
__device__ __forceinline__ float elu1(float x)  { return x > 0.f ? x : (expf(x) - 1.f); }

// Device-scope grid barrier (all NBLK blocks co-resident by construction).
// Counter is monotonically increasing; barrier k waits for count >= k*NBLK.
// Counter is zeroed by a hipMemsetAsync node before each kernel launch.
__device__ __forceinline__ void grid_barrier(unsigned* cnt, unsigned target) {
    __syncthreads();
    if (threadIdx.x == 0) {
        __threadfence();                       // release: flush L1/L2 writes
        atomicAdd(cnt, 1u);
        while (atomicAdd(cnt, 0u) < target) __builtin_amdgcn_s_sleep(2);
        __threadfence();                       // acquire: invalidate stale lines
    }
    __syncthreads();
}

union SMem {
    struct {                      // phase C (attention + adjacency)
        float e[2][4][32];        // [which][t][v]
        float att[4][32][32];     // [t][i][j]
        float adj[1024];          // [i][u]
        float a[1152];            // a_temporal slice for this head
        float red[256];
        float d12[32];
        float mnmx[2];
    } p1;
    struct {                      // phase main
        float C[4][1024];         // [hd][j*32+u]
        float W[4][8][32];        // [hd][dm][j]
    } p2;
};

// ---------------------------------------------------------------------------
// Phase C: one block per (n, hd), blocks 0..15. Computes:
//   - adjn (B+I, min-max, D^-1/2 sym norm) in LDS
//   - Wh on the fly from x (and spills it to ws for the main phase)
//   - ei/ej separable attention logits, softmax over t, C = att^T * adjn
// ---------------------------------------------------------------------------
__device__ void phaseC(const float* __restrict__ xin,
                       const float* __restrict__ mw_l,
                       const float* __restrict__ mb_l,
                       const float* __restrict__ a_l,
                       const float* __restrict__ Bp_l,
                       float* __restrict__ Whv,
                       float* __restrict__ Cbuf,
                       SMem& sm) {
    int b = blockIdx.x;           // hd*4 + n
    int n = b & 3, hd = b >> 2;
    int tid = threadIdx.x;

    // ---- adjacency into sm.p1.adj ----
    const float* B = Bp_l + hd * 1024;
    float lmin = 1e30f, lmax = -1e30f;
    for (int p = tid; p < 1024; p += 256) {
        int i = p >> 5, j = p & 31;
        float val = B[p] + (i == j ? 1.f : 0.f);
        sm.p1.adj[p] = val;
        lmin = fminf(lmin, val);
        lmax = fmaxf(lmax, val);
    }
    for (int p = tid; p < 1152; p += 256) sm.p1.a[p] = a_l[hd * 1152 + p];
    sm.p1.red[tid] = lmin; __syncthreads();
    for (int s = 128; s > 0; s >>= 1) { if (tid < s) sm.p1.red[tid] = fminf(sm.p1.red[tid], sm.p1.red[tid + s]); __syncthreads(); }
    if (tid == 0) sm.p1.mnmx[0] = sm.p1.red[0];
    __syncthreads();
    sm.p1.red[tid] = lmax; __syncthreads();
    for (int s = 128; s > 0; s >>= 1) { if (tid < s) sm.p1.red[tid] = fmaxf(sm.p1.red[tid], sm.p1.red[tid + s]); __syncthreads(); }
    if (tid == 0) sm.p1.mnmx[1] = sm.p1.red[0];
    __syncthreads();
    float mn = sm.p1.mnmx[0], inv = 1.f / (sm.p1.mnmx[1] - mn);
    for (int p = tid; p < 1024; p += 256) sm.p1.adj[p] = (sm.p1.adj[p] - mn) * inv;
    __syncthreads();
    if (tid < 32) {
        float s = 0.f;
        for (int j = 0; j < 32; ++j) s += sm.p1.adj[tid * 32 + j];
        sm.p1.d12[tid] = rsqrtf(s);
    }
    __syncthreads();
    for (int p = tid; p < 1024; p += 256) {
        int i = p >> 5, j = p & 31;
        sm.p1.adj[p] = sm.p1.d12[i] * sm.p1.adj[p] * sm.p1.d12[j];
    }

    // ---- stage A: ei/ej with on-the-fly Wh; which==0 spills Wh to ws ----
    int which = tid >> 7;         // wave-uniform (waves 0,1 vs 2,3)
    int t     = (tid >> 5) & 3;
    int v     = tid & 31;
    float w[16], bb[4];
#pragma unroll
    for (int q = 0; q < 16; ++q) w[q] = mw_l[hd * 16 + q];
#pragma unroll
    for (int q = 0; q < 4; ++q) bb[q] = mb_l[hd * 4 + q];
    const float* aw = &sm.p1.a[which * 96];
    __syncthreads();              // a-slice + adj ready
    float acc = 0.f;
    for (int mp = 0; mp < 144; ++mp) {
        int hpr = mp / 24, ww = mp % 24;
        int m = t * 144 + mp;
        const float* xp = xin + ((size_t)(n * MM + m) * 4) * 32 + v;
        float x0 = xp[0], x1 = xp[32], x2 = xp[64], x3 = xp[96];
#pragma unroll
        for (int tt = 0; tt < 4; ++tt) {
            float wh = bb[tt] + x0 * w[0 * 4 + tt] + x1 * w[1 * 4 + tt]
                              + x2 * w[2 * 4 + tt] + x3 * w[3 * 4 + tt];
            acc += wh * aw[hpr * 192 + ww * 4 + tt];
            if (which == 0)
                Whv[((size_t)((hd * 4 + n) * 4 + tt) * MM + m) * 32 + v] = wh;
        }
    }
    sm.p1.e[which][t][v] = acc;
    __syncthreads();

    // ---- stage B: att[t][i][j] = softmax_t(lrelu(ei[i,t]+ej[j,t])) ----
    for (int p = tid; p < 1024; p += 256) {
        int i = p >> 5, j = p & 31;
        float e[4], mx = -1e30f;
#pragma unroll
        for (int q = 0; q < 4; ++q) {
            e[q] = lrelu(sm.p1.e[0][q][i] + sm.p1.e[1][q][j]);
            mx = fmaxf(mx, e[q]);
        }
        float s = 0.f;
#pragma unroll
        for (int q = 0; q < 4; ++q) { e[q] = expf(e[q] - mx); s += e[q]; }
        float invs = 1.f / s;
#pragma unroll
        for (int q = 0; q < 4; ++q) sm.p1.att[q][i][j] = e[q] * invs;
    }
    __syncthreads();

    // ---- stage C: C[t][j][u] = sum_i att[t][i][j] * adj[i][u] ----
    float* Cb = Cbuf + (size_t)(hd * 4 + n) * 4 * 1024;
    for (int p = tid; p < 1024; p += 256) {
        int j = p >> 5, u = p & 31;
        float c0 = 0.f, c1 = 0.f, c2 = 0.f, c3 = 0.f;
        for (int i = 0; i < 32; ++i) {
            float av = sm.p1.adj[i * 32 + u];
            c0 += sm.p1.att[0][i][j] * av;
            c1 += sm.p1.att[1][i][j] * av;
            c2 += sm.p1.att[2][i][j] * av;
            c3 += sm.p1.att[3][i][j] * av;
        }
        Cb[0 * 1024 + j * 32 + u] = c0;
        Cb[1 * 1024 + j * 32 + u] = c1;
        Cb[2 * 1024 + j * 32 + u] = c2;
        Cb[3 * 1024 + j * 32 + u] = c3;
    }
}

// ---------------------------------------------------------------------------
// Phase main: 64 blocks = (n, t, mc of 144 rows). 18 iters of 8 rows:
//   out[n,m,t,u] = 0.25 * sum_hd elu(sum_j Wh[hd,n,t,m,j] * C[hd,n,t,j,u])
// ---------------------------------------------------------------------------
__device__ void phaseMain(const float* __restrict__ Whv,
                          const float* __restrict__ Cbuf,
                          float* __restrict__ xout,
                          SMem& sm) {
    int b = blockIdx.x;           // n*16 + t*4 + mc
    int mc = b & 3, t = (b >> 2) & 3, n = b >> 4;
    int tid = threadIdx.x;

    for (int p = tid; p < 4096; p += 256) {
        int hd = p >> 10, r = p & 1023;
        sm.p2.C[hd][r] = Cbuf[(size_t)((hd * 4 + n) * 4 + t) * 1024 + r];
    }
    int dm = tid >> 5, u = tid & 31;
    for (int it = 0; it < 18; ++it) {
        int m0 = mc * 144 + it * 8;
        __syncthreads();
        for (int p = tid; p < 1024; p += 256) {
            int hd = p >> 8, q = p & 255, dmm = q >> 5, j = q & 31;
            sm.p2.W[hd][dmm][j] = Whv[((size_t)((hd * 4 + n) * 4 + t) * MM + m0 + dmm) * 32 + j];
        }
        __syncthreads();
        float acc = 0.f;
#pragma unroll
        for (int hd = 0; hd < 4; ++hd) {
            float s = 0.f;
#pragma unroll
            for (int j = 0; j < 32; ++j) s += sm.p2.W[hd][dm][j] * sm.p2.C[hd][j * 32 + u];
            acc += elu1(s);
        }
        xout[((size_t)(n * MM + m0 + dm) * 4 + t) * 32 + u] = 0.25f * acc;
    }
}

// ---------------------------------------------------------------------------
__global__ __launch_bounds__(256) void fused_kernel(const float* __restrict__ x,
                                                    const float* __restrict__ map_w,
                                                    const float* __restrict__ map_b,
                                                    const float* __restrict__ a_temp,
                                                    const float* __restrict__ Bp,
                                                    float* __restrict__ out,
                                                    float* __restrict__ ws,
                                                    unsigned* __restrict__ cnt) {
    __shared__ SMem sm;
    float* Whv   = ws;                  // 1,179,648 floats
    float* Cbuf  = Whv + 1179648;       //    65,536
    float* inter = Cbuf + 65536;        //   294,912

    if (blockIdx.x < 16)
        phaseC(x, map_w, map_b, a_temp, Bp, Whv, Cbuf, sm);
    grid_barrier(cnt, NBLK);
    phaseMain(Whv, Cbuf, inter, sm);
    grid_barrier(cnt, 2 * NBLK);
    if (blockIdx.x < 16)
        phaseC(inter, map_w + 64, map_b + 16, a_temp + 4608, Bp + 4096, Whv, Cbuf, sm);
    grid_barrier(cnt, 3 * NBLK);
    phaseMain(Whv, Cbuf, out, sm);
}

// ---------------------------------------------------------------------------
extern "C" void kernel_launch(void* const* d_in, const int* in_sizes, int n_in,
                              void* d_out, int out_size, void* d_ws, size_t ws_size,
                              hipStream_t stream) {
    const float* x      = (const float*)d_in[0];
    const float* map_w  = (const float*)d_in[1];   // (2,4,4,4)
    const float* map_b  = (const float*)d_in[2];   // (2,4,4)
    const float* a_temp = (const float*)d_in[3];   // (2,4,1152)
    const float* Bp     = (const float*)d_in[4];   // (2,4,32,32)
    float* out = (float*)d_out;
    float* ws  = (float*)d_ws;

    unsigned* cnt = (unsigned*)(ws + 1179648 + 65536 + 294912);
    hipMemsetAsync(cnt, 0, 64, stream);
    fused_kernel<<<NBLK, 256, 0, stream>>>(x, map_w, map_b, a_temp, Bp, out, ws, cnt);
}

// Round 3
// 115.247 us; speedup vs baseline: 2.0548x; 2.0548x over previous
//
#include <hip/hip_runtime.h>

#define MM 576      // H*W
#define NBLK 128    // grid size; <= 256 so all blocks co-resident (1 block/CU)

__device__ __forceinline__ float lrelu(float x) { return x > 0.f ? x : 0.2f * x; }
__device__ __forceinline__ float elu1(float x)  { return x > 0.f ? x : (expf(x) - 1.f); }

// Grid barrier: one arrival RMW per block, then LOAD-only polling (agent scope).
// cnt is zeroed by a hipMemsetAsync node before each launch; targets are
// monotonic multiples of NBLK so the counter never needs mid-kernel reset.
__device__ __forceinline__ void grid_barrier(unsigned* cnt, unsigned target) {
    __syncthreads();
    if (threadIdx.x == 0) {
        __threadfence();   // release: drain stores, writeback L2 (device scope)
        __hip_atomic_fetch_add(cnt, 1u, __ATOMIC_RELAXED, __HIP_MEMORY_SCOPE_AGENT);
        while (__hip_atomic_load(cnt, __ATOMIC_RELAXED, __HIP_MEMORY_SCOPE_AGENT) < target)
            __builtin_amdgcn_s_sleep(4);
        __threadfence();   // acquire: invalidate stale cached lines
    }
    __syncthreads();
}

union SMem {
    struct { float part[8][32]; } p1;                                   // 1 KB
    struct {
        float adj[1024]; float att[1024]; float e[2][4][32];
        float red[256]; float d12[32]; float mnmx[2];
    } p2;                                                               // ~9.3 KB
    struct { float C[4][1024]; float W[2][4][8][32]; } p3;              // 24 KB
};

// ---------------------------------------------------------------------------
// P1: 128 blocks = (hd, n, t, which). Computes Wh on the fly from x,
// spills it (which==0 blocks), and reduces the separable attention logit
//   e[which][t][v] = sum_{r<144, tt} Wh[v, t*144+r, tt] * a[which*96 + (r/24)*192 + (r%24)*4 + tt]
// ---------------------------------------------------------------------------
__device__ void phase1(const float* __restrict__ xin,
                       const float* __restrict__ mw_l,
                       const float* __restrict__ mb_l,
                       const float* __restrict__ a_l,
                       float* __restrict__ Whv,
                       float* __restrict__ epart,
                       SMem& sm) {
    int b = blockIdx.x;
    int hd = b >> 5, n = (b >> 3) & 3, t = (b >> 1) & 3, which = b & 1;
    int tid = threadIdx.x;
    int sub = tid >> 5, v = tid & 31;

    float w[16], bb[4];
#pragma unroll
    for (int q = 0; q < 16; ++q) w[q] = mw_l[hd * 16 + q];
#pragma unroll
    for (int q = 0; q < 4; ++q) bb[q] = mb_l[hd * 4 + q];

    const float* aw = a_l + hd * 1152 + which * 96;
    float acc = 0.f;
    int r0 = sub * 18;
#pragma unroll 6
    for (int mp = 0; mp < 18; ++mp) {
        int r = r0 + mp;                 // [0,144)
        int dh = r / 24, wcol = r % 24;
        int m = t * 144 + r;
        const float* xp = xin + ((size_t)(n * MM + m) * 4) * 32 + v;
        float x0 = xp[0], x1 = xp[32], x2 = xp[64], x3 = xp[96];
#pragma unroll
        for (int tt = 0; tt < 4; ++tt) {
            float wh = fmaf(x0, w[tt], fmaf(x1, w[4 + tt],
                        fmaf(x2, w[8 + tt], fmaf(x3, w[12 + tt], bb[tt]))));
            acc = fmaf(wh, aw[dh * 192 + wcol * 4 + tt], acc);
            if (which == 0)   // block-uniform: no divergence
                Whv[(((size_t)(hd * 4 + n) * 4 + tt) * MM + m) * 32 + v] = wh;
        }
    }
    sm.p1.part[sub][v] = acc;
    __syncthreads();
    if (tid < 32) {
        float e = 0.f;
#pragma unroll
        for (int s = 0; s < 8; ++s) e += sm.p1.part[s][tid];
        epart[(size_t)((hd * 4 + n) * 4 + t) * 64 + which * 32 + tid] = e;
    }
}

// ---------------------------------------------------------------------------
// P2: 64 blocks = (hd, n, t). adj-norm from Bp, softmax over q (keep q==t),
// C[t][j][u] = sum_i att[i][j] * adjn[i][u].
// ---------------------------------------------------------------------------
__device__ void phase2(const float* __restrict__ Bp_l,
                       const float* __restrict__ epart,
                       float* __restrict__ Cbuf,
                       SMem& sm) {
    int b = blockIdx.x;
    int hd = b >> 4, n = (b >> 2) & 3, t = b & 3;
    int tid = threadIdx.x;

    const float* B = Bp_l + hd * 1024;
    float lmin = 1e30f, lmax = -1e30f;
    for (int p = tid; p < 1024; p += 256) {
        int i = p >> 5, j = p & 31;
        float val = B[p] + (i == j ? 1.f : 0.f);
        sm.p2.adj[p] = val;
        lmin = fminf(lmin, val);
        lmax = fmaxf(lmax, val);
    }
    {   // e: 256 floats, one per thread
        int q = tid >> 6, rest = tid & 63, wh = rest >> 5, i = rest & 31;
        sm.p2.e[wh][q][i] = epart[(size_t)((hd * 4 + n) * 4 + q) * 64 + rest];
    }
    sm.p2.red[tid] = lmin; __syncthreads();
    for (int s = 128; s > 0; s >>= 1) { if (tid < s) sm.p2.red[tid] = fminf(sm.p2.red[tid], sm.p2.red[tid + s]); __syncthreads(); }
    if (tid == 0) sm.p2.mnmx[0] = sm.p2.red[0];
    __syncthreads();
    sm.p2.red[tid] = lmax; __syncthreads();
    for (int s = 128; s > 0; s >>= 1) { if (tid < s) sm.p2.red[tid] = fmaxf(sm.p2.red[tid], sm.p2.red[tid + s]); __syncthreads(); }
    if (tid == 0) sm.p2.mnmx[1] = sm.p2.red[0];
    __syncthreads();
    float mn = sm.p2.mnmx[0], inv = 1.f / (sm.p2.mnmx[1] - mn);
    for (int p = tid; p < 1024; p += 256) sm.p2.adj[p] = (sm.p2.adj[p] - mn) * inv;
    __syncthreads();
    if (tid < 32) {
        float s = 0.f;
        for (int j = 0; j < 32; ++j) s += sm.p2.adj[tid * 32 + j];
        sm.p2.d12[tid] = rsqrtf(s);
    }
    __syncthreads();
    for (int p = tid; p < 1024; p += 256) {
        int i = p >> 5, j = p & 31;
        sm.p2.adj[p] = sm.p2.d12[i] * sm.p2.adj[p] * sm.p2.d12[j];
    }
    // att[i][j] = softmax_q(lrelu(e0[q][i]+e1[q][j]))[q==t]
    for (int p = tid; p < 1024; p += 256) {
        int i = p >> 5, j = p & 31;
        float e[4], mx = -1e30f;
#pragma unroll
        for (int q = 0; q < 4; ++q) {
            e[q] = lrelu(sm.p2.e[0][q][i] + sm.p2.e[1][q][j]);
            mx = fmaxf(mx, e[q]);
        }
        float s = 0.f;
#pragma unroll
        for (int q = 0; q < 4; ++q) { e[q] = expf(e[q] - mx); s += e[q]; }
        sm.p2.att[p] = e[t] / s;
    }
    __syncthreads();
    float* Cb = Cbuf + (size_t)((hd * 4 + n) * 4 + t) * 1024;
    for (int p = tid; p < 1024; p += 256) {
        int j = p >> 5, u = p & 31;
        float c = 0.f;
        for (int i = 0; i < 32; ++i)
            c = fmaf(sm.p2.att[i * 32 + j], sm.p2.adj[i * 32 + u], c);
        Cb[p] = c;
    }
}

// ---------------------------------------------------------------------------
// P3: 128 blocks = (n, t, mc of 72 rows). Single-sync double-buffered tiles:
//   out[n,m,t,u] = 0.25 * sum_hd elu(sum_j Wh[hd,n,t,m,j] * C[hd,n,t,j,u])
// ---------------------------------------------------------------------------
__device__ void phase3(const float* __restrict__ Whv,
                       const float* __restrict__ Cbuf,
                       float* __restrict__ xout,
                       SMem& sm) {
    int b = blockIdx.x;
    int mc = b & 7, t = (b >> 3) & 3, n = b >> 5;
    int tid = threadIdx.x;

    for (int p = tid; p < 4096; p += 256) {
        int hd = p >> 10, r = p & 1023;
        sm.p3.C[hd][r] = Cbuf[(size_t)((hd * 4 + n) * 4 + t) * 1024 + r];
    }

    int dm = tid >> 5, u = tid & 31;    // also (dmm, j) for tile loads
    int m0 = mc * 72;
    size_t wb[4];
#pragma unroll
    for (int hd = 0; hd < 4; ++hd)
        wb[hd] = ((size_t)(hd * 4 + n) * 4 + t) * MM * 32;

    float r0, r1, r2, r3;
    {
        size_t mo = (size_t)(m0 + dm) * 32 + u;
        r0 = Whv[wb[0] + mo]; r1 = Whv[wb[1] + mo];
        r2 = Whv[wb[2] + mo]; r3 = Whv[wb[3] + mo];
    }
    sm.p3.W[0][0][dm][u] = r0; sm.p3.W[0][1][dm][u] = r1;
    sm.p3.W[0][2][dm][u] = r2; sm.p3.W[0][3][dm][u] = r3;

    int cur = 0;
    for (int it = 0; it < 9; ++it) {
        if (it + 1 < 9) {
            size_t mo = (size_t)(m0 + (it + 1) * 8 + dm) * 32 + u;
            r0 = Whv[wb[0] + mo]; r1 = Whv[wb[1] + mo];
            r2 = Whv[wb[2] + mo]; r3 = Whv[wb[3] + mo];
        }
        __syncthreads();   // tile `cur` (and C on it==0) visible to all
        float acc = 0.f;
#pragma unroll
        for (int hd = 0; hd < 4; ++hd) {
            float s = 0.f;
#pragma unroll
            for (int jj = 0; jj < 32; ++jj)
                s = fmaf(sm.p3.W[cur][hd][dm][jj], sm.p3.C[hd][jj * 32 + u], s);
            acc += elu1(s);
        }
        int m = m0 + it * 8 + dm;
        xout[((size_t)(n * MM + m) * 4 + t) * 32 + u] = 0.25f * acc;
        if (it + 1 < 9) {
            sm.p3.W[cur ^ 1][0][dm][u] = r0; sm.p3.W[cur ^ 1][1][dm][u] = r1;
            sm.p3.W[cur ^ 1][2][dm][u] = r2; sm.p3.W[cur ^ 1][3][dm][u] = r3;
        }
        cur ^= 1;
    }
}

// ---------------------------------------------------------------------------
__global__ __launch_bounds__(256) void fused_kernel(const float* __restrict__ x,
                                                    const float* __restrict__ map_w,
                                                    const float* __restrict__ map_b,
                                                    const float* __restrict__ a_temp,
                                                    const float* __restrict__ Bp,
                                                    float* __restrict__ out,
                                                    float* __restrict__ ws,
                                                    unsigned* __restrict__ cnt) {
    __shared__ SMem sm;
    float* Whv   = ws;                  // 1,179,648 floats
    float* Cbuf  = Whv + 1179648;       //    65,536
    float* inter = Cbuf + 65536;        //   294,912
    float* epart = inter + 294912;      //     4,096

    phase1(x, map_w, map_b, a_temp, Whv, epart, sm);
    grid_barrier(cnt, NBLK);
    if (blockIdx.x < 64) phase2(Bp, epart, Cbuf, sm);
    grid_barrier(cnt, 2 * NBLK);
    phase3(Whv, Cbuf, inter, sm);
    grid_barrier(cnt, 3 * NBLK);
    phase1(inter, map_w + 64, map_b + 16, a_temp + 4608, Whv, epart, sm);
    grid_barrier(cnt, 4 * NBLK);
    if (blockIdx.x < 64) phase2(Bp + 4096, epart, Cbuf, sm);
    grid_barrier(cnt, 5 * NBLK);
    phase3(Whv, Cbuf, out, sm);
}

// ---------------------------------------------------------------------------
extern "C" void kernel_launch(void* const* d_in, const int* in_sizes, int n_in,
                              void* d_out, int out_size, void* d_ws, size_t ws_size,
                              hipStream_t stream) {
    const float* x      = (const float*)d_in[0];
    const float* map_w  = (const float*)d_in[1];   // (2,4,4,4)
    const float* map_b  = (const float*)d_in[2];   // (2,4,4)
    const float* a_temp = (const float*)d_in[3];   // (2,4,1152)
    const float* Bp     = (const float*)d_in[4];   // (2,4,32,32)
    float* out = (float*)d_out;
    float* ws  = (float*)d_ws;

    unsigned* cnt = (unsigned*)(ws + 1179648 + 65536 + 294912 + 4096);
    hipMemsetAsync(cnt, 0, 64, stream);
    fused_kernel<<<NBLK, 256, 0, stream>>>(x, map_w, map_b, a_temp, Bp, out, ws, cnt);
}